// Round 1
// baseline (2381.424 us; speedup 1.0000x reference)
//
#include <hip/hip_runtime.h>
#include <cmath>

// ---------------------------------------------------------------------------
// GCN: out = log_softmax(conv5(relu-chain...)), emb = h after 3rd relu.
// Per conv: g = (h @ W) * dinv[row];  h' = dinv[v]*(sum_{u->v} g[u] + g[v]) + b
// CSR built on-device each call (deterministic work; fp sum order may vary
// slightly via atomic placement, within threshold).
// ---------------------------------------------------------------------------

__global__ void count_deg_kernel(const int* __restrict__ dst, int* __restrict__ deg, int e) {
  int i = blockIdx.x * blockDim.x + threadIdx.x;
  int stride = gridDim.x * blockDim.x;
  for (; i < e; i += stride) atomicAdd(&deg[dst[i]], 1);
}

__global__ void dinv_kernel(const int* __restrict__ deg, float* __restrict__ dinv, int n) {
  int i = blockIdx.x * blockDim.x + threadIdx.x;
  if (i < n) dinv[i] = rsqrtf((float)deg[i] + 1.0f);
}

#define SCAN_T 1024
__global__ void scan_blocks_kernel(const int* __restrict__ deg, int* __restrict__ rs,
                                   int* __restrict__ bsum, int n) {
  __shared__ int s[SCAN_T];
  int t = threadIdx.x;
  int i = blockIdx.x * SCAN_T + t;
  int own = (i < n) ? deg[i] : 0;
  s[t] = own;
  for (int off = 1; off < SCAN_T; off <<= 1) {
    __syncthreads();
    int add = (t >= off) ? s[t - off] : 0;
    __syncthreads();
    s[t] += add;
  }
  if (i < n) rs[i] = s[t] - own;          // exclusive within block
  if (t == SCAN_T - 1) bsum[blockIdx.x] = s[t];
}

__global__ void scan_bsum_kernel(int* __restrict__ bsum, int nb) {
  __shared__ int s[128];
  int t = threadIdx.x;
  int v = (t < nb) ? bsum[t] : 0;
  s[t] = v;
  for (int off = 1; off < 128; off <<= 1) {
    __syncthreads();
    int add = (t >= off) ? s[t - off] : 0;
    __syncthreads();
    s[t] += add;
  }
  if (t < nb) bsum[t] = s[t] - v;         // exclusive block offsets
}

__global__ void add_off_kernel(int* __restrict__ rs, const int* __restrict__ bsum, int n) {
  int i = blockIdx.x * blockDim.x + threadIdx.x;
  if (i < n) rs[i] += bsum[i >> 10];
}

__global__ void fill_csr_kernel(const int* __restrict__ src, const int* __restrict__ dst,
                                const int* __restrict__ rs, int* __restrict__ cursor,
                                int* __restrict__ col, int e) {
  int i = blockIdx.x * blockDim.x + threadIdx.x;
  int stride = gridDim.x * blockDim.x;
  for (; i < e; i += stride) {
    int d = dst[i];
    int p = rs[d] + atomicAdd(&cursor[d], 1);
    col[p] = src[i];
  }
}

// ---------------------------------------------------------------------------
// GEMM: G[r, :256] = (A[r, :K] @ W[:K, :256]) * dinv[r]
// BM=128, BN=128, BK=32, 256 threads, 8x8 micro-tile.
// ---------------------------------------------------------------------------
#define BM 128
#define BN 128
#define BK 32

template <int K>
__global__ __launch_bounds__(256, 3) void gemm_scaled_kernel(
    const float* __restrict__ A, const float* __restrict__ W,
    const float* __restrict__ dinv, float* __restrict__ G, int n) {
  __shared__ float As[BK][BM + 4];   // row stride 132 floats (528B, 16B-aligned)
  __shared__ float Bs[BK][BN];
  const int M = 256;
  int tid = threadIdx.x;
  int tx = tid & 15, ty = tid >> 4;
  int rowBase = blockIdx.y * BM;
  int colBase = blockIdx.x * BN;

  float acc[8][8];
#pragma unroll
  for (int i = 0; i < 8; i++)
#pragma unroll
    for (int j = 0; j < 8; j++) acc[i][j] = 0.f;

  for (int kt = 0; kt < K; kt += BK) {
    // A tile: 128 rows x 32 k, transposed into As[k][m]
#pragma unroll
    for (int i = 0; i < 4; i++) {
      int s = tid + i * 256;       // 0..1023
      int r = s >> 3;              // 0..127
      int kq = (s & 7) * 4;        // 0..28
      int gr = rowBase + r;
      float4 v = make_float4(0.f, 0.f, 0.f, 0.f);
      if (gr < n) v = *(const float4*)(A + (size_t)gr * K + kt + kq);
      As[kq + 0][r] = v.x;
      As[kq + 1][r] = v.y;
      As[kq + 2][r] = v.z;
      As[kq + 3][r] = v.w;
    }
    // B tile: 32 k x 128 n
#pragma unroll
    for (int i = 0; i < 4; i++) {
      int s = tid + i * 256;       // 0..1023
      int kr = s >> 5;             // 0..31
      int nq = (s & 31) * 4;       // 0..124
      *(float4*)&Bs[kr][nq] = *(const float4*)(W + (size_t)(kt + kr) * M + colBase + nq);
    }
    __syncthreads();
#pragma unroll
    for (int kk = 0; kk < BK; kk++) {
      float a[8], b[8];
      *(float4*)&a[0] = *(const float4*)&As[kk][ty * 8];
      *(float4*)&a[4] = *(const float4*)&As[kk][ty * 8 + 4];
      *(float4*)&b[0] = *(const float4*)&Bs[kk][tx * 8];
      *(float4*)&b[4] = *(const float4*)&Bs[kk][tx * 8 + 4];
#pragma unroll
      for (int i = 0; i < 8; i++)
#pragma unroll
        for (int j = 0; j < 8; j++) acc[i][j] += a[i] * b[j];
    }
    __syncthreads();
  }

#pragma unroll
  for (int i = 0; i < 8; i++) {
    int gr = rowBase + ty * 8 + i;
    if (gr < n) {
      float sc = dinv[gr];
#pragma unroll
      for (int j = 0; j < 8; j += 4) {
        float4 v;
        v.x = acc[i][j + 0] * sc;
        v.y = acc[i][j + 1] * sc;
        v.z = acc[i][j + 2] * sc;
        v.w = acc[i][j + 3] * sc;
        *(float4*)(G + (size_t)gr * M + colBase + tx * 8 + j) = v;
      }
    }
  }
}

// ---------------------------------------------------------------------------
// Aggregate 256-dim: one wave per node, float4 per lane.
// H[v] = relu?( dinv[v]*(sum_{u->v} G[u] + G[v]) + bias )
// ---------------------------------------------------------------------------
__global__ __launch_bounds__(256) void aggregate256_kernel(
    const float* __restrict__ G, const int* __restrict__ col,
    const int* __restrict__ rs, const int* __restrict__ deg,
    const float* __restrict__ dinv, const float* __restrict__ bias,
    float* __restrict__ H, int n, int do_relu) {
  int wid = threadIdx.x >> 6;
  int lane = threadIdx.x & 63;
  int v = blockIdx.x * 4 + wid;
  if (v >= n) return;
  const float4* Gv = (const float4*)G;
  float4 acc = Gv[(size_t)v * 64 + lane];
  int base = rs[v], cnt = deg[v];
  for (int i = 0; i < cnt; i++) {
    int u = col[base + i];
    float4 m = Gv[(size_t)u * 64 + lane];
    acc.x += m.x; acc.y += m.y; acc.z += m.z; acc.w += m.w;
  }
  float s = dinv[v];
  float4 b4 = ((const float4*)bias)[lane];
  float4 o;
  o.x = acc.x * s + b4.x;
  o.y = acc.y * s + b4.y;
  o.z = acc.z * s + b4.z;
  o.w = acc.w * s + b4.w;
  if (do_relu) {
    o.x = fmaxf(o.x, 0.f); o.y = fmaxf(o.y, 0.f);
    o.z = fmaxf(o.z, 0.f); o.w = fmaxf(o.w, 0.f);
  }
  ((float4*)H)[(size_t)v * 64 + lane] = o;
}

// ---------------------------------------------------------------------------
// Final GEMM (K=256, M=40): one wave per row, W2 staged in LDS.
// G2[r, c] = (A[r,:] @ W2[:, c]) * dinv[r]
// ---------------------------------------------------------------------------
__global__ __launch_bounds__(256) void gemm40_kernel(
    const float* __restrict__ A, const float* __restrict__ W2,
    const float* __restrict__ dinv, float* __restrict__ G2, int n) {
  __shared__ float Ws[256 * 40];
  for (int i = threadIdx.x; i < 256 * 40; i += 256) Ws[i] = W2[i];
  __syncthreads();
  int wid = threadIdx.x >> 6;
  int lane = threadIdx.x & 63;
  int r = blockIdx.x * 4 + wid;
  if (r >= n) return;
  if (lane < 40) {
    const float* Ar = A + (size_t)r * 256;
    float acc = 0.f;
#pragma unroll 4
    for (int k = 0; k < 256; k += 4) {
      float4 a = *(const float4*)(Ar + k);
      acc += a.x * Ws[(k + 0) * 40 + lane];
      acc += a.y * Ws[(k + 1) * 40 + lane];
      acc += a.z * Ws[(k + 2) * 40 + lane];
      acc += a.w * Ws[(k + 3) * 40 + lane];
    }
    G2[(size_t)r * 40 + lane] = acc * dinv[r];
  }
}

// ---------------------------------------------------------------------------
// Aggregate 40-dim + bias + log_softmax. One wave per node, lanes 0..39.
// ---------------------------------------------------------------------------
__global__ __launch_bounds__(256) void agg40_lsm_kernel(
    const float* __restrict__ G2, const int* __restrict__ col,
    const int* __restrict__ rs, const int* __restrict__ deg,
    const float* __restrict__ dinv, const float* __restrict__ b2,
    float* __restrict__ out, int n) {
  int wid = threadIdx.x >> 6;
  int lane = threadIdx.x & 63;
  int v = blockIdx.x * 4 + wid;
  if (v >= n) return;
  bool act = lane < 40;
  float acc = 0.f;
  if (act) acc = G2[(size_t)v * 40 + lane];
  int base = rs[v], cnt = deg[v];
  for (int i = 0; i < cnt; i++) {
    int u = col[base + i];
    if (act) acc += G2[(size_t)u * 40 + lane];
  }
  float val;
  if (act) val = acc * dinv[v] + b2[lane];
  else val = -INFINITY;
  float m = val;
  for (int off = 32; off; off >>= 1) m = fmaxf(m, __shfl_xor(m, off, 64));
  float e = act ? expf(val - m) : 0.f;
  float ssum = e;
  for (int off = 32; off; off >>= 1) ssum += __shfl_xor(ssum, off, 64);
  if (act) out[(size_t)v * 40 + lane] = val - m - logf(ssum);
}

// ---------------------------------------------------------------------------

static inline size_t alignup(size_t x) { return (x + 255) & ~(size_t)255; }

extern "C" void kernel_launch(void* const* d_in, const int* in_sizes, int n_in,
                              void* d_out, int out_size, void* d_ws, size_t ws_size,
                              hipStream_t stream) {
  const float* x  = (const float*)d_in[0];
  const int*   ei = (const int*)d_in[1];
  const float* W1 = (const float*)d_in[2];
  const float* b1 = (const float*)d_in[3];
  const float* Wi = (const float*)d_in[4];
  const float* bi = (const float*)d_in[5];
  const float* W2 = (const float*)d_in[6];
  const float* b2 = (const float*)d_in[7];

  const int in_d = 512, mid_d = 256, out_d = 40;
  int n = in_sizes[0] / in_d;       // 100000
  int E = in_sizes[1] / 2;          // 1600000
  const int* src = ei;
  const int* dst = ei + E;

  float* out_lsm = (float*)d_out;                        // n*40
  float* emb     = (float*)d_out + (size_t)n * out_d;    // n*256 (h ping-pong + final emb)

  // workspace layout
  char* w = (char*)d_ws;
  float* dinv  = (float*)w;  w += alignup((size_t)n * 4);
  int* deg     = (int*)w;    w += alignup((size_t)n * 4);
  int* rs      = (int*)w;    w += alignup((size_t)n * 4);
  int* cursor  = (int*)w;    w += alignup((size_t)n * 4);
  int* colidx  = (int*)w;    w += alignup((size_t)E * 4);
  int* bsum    = (int*)w;    w += alignup(128 * 4);
  float* bufA  = (float*)w;  w += alignup((size_t)n * mid_d * 4);   // g buffer (also g2)

  int nb = (n + SCAN_T - 1) / SCAN_T;   // 98

  // --- graph build ---
  hipMemsetAsync(deg, 0, (size_t)n * 4, stream);
  hipMemsetAsync(cursor, 0, (size_t)n * 4, stream);
  count_deg_kernel<<<2048, 256, 0, stream>>>(dst, deg, E);
  dinv_kernel<<<(n + 255) / 256, 256, 0, stream>>>(deg, dinv, n);
  scan_blocks_kernel<<<nb, SCAN_T, 0, stream>>>(deg, rs, bsum, n);
  scan_bsum_kernel<<<1, 128, 0, stream>>>(bsum, nb);
  add_off_kernel<<<(n + 255) / 256, 256, 0, stream>>>(rs, bsum, n);
  fill_csr_kernel<<<2048, 256, 0, stream>>>(src, dst, rs, cursor, colidx, E);

  dim3 ggrid(256 / BN, (n + BM - 1) / BM);   // (2, 782)
  int agg_grid = (n + 3) / 4;

  // --- conv1: x(512) -> h(256), bias b1, no relu ---
  gemm_scaled_kernel<512><<<ggrid, 256, 0, stream>>>(x, W1, dinv, bufA, n);
  aggregate256_kernel<<<agg_grid, 256, 0, stream>>>(bufA, colidx, rs, deg, dinv, b1, emb, n, 0);

  // --- conv2..4: h(256) -> h(256), bias bi, relu ---
  for (int l = 0; l < 3; l++) {
    gemm_scaled_kernel<256><<<ggrid, 256, 0, stream>>>(emb, Wi, dinv, bufA, n);
    aggregate256_kernel<<<agg_grid, 256, 0, stream>>>(bufA, colidx, rs, deg, dinv, bi, emb, n, 1);
  }
  // emb region now holds final embedding (relu'd) == output 1.

  // --- conv5: h(256) -> 40, bias b2, log_softmax ---
  gemm40_kernel<<<agg_grid, 256, 0, stream>>>(emb, W2, dinv, bufA, n);
  agg40_lsm_kernel<<<agg_grid, 256, 0, stream>>>(bufA, colidx, rs, deg, dinv, b2, out_lsm, n);
}

// Round 2
// 1386.641 us; speedup vs baseline: 1.7174x; 1.7174x over previous
//
#include <hip/hip_runtime.h>
#include <cmath>

typedef __attribute__((ext_vector_type(8))) short short8v;
typedef __attribute__((ext_vector_type(4))) short short4v;
typedef __attribute__((ext_vector_type(4))) float f32x4;

__device__ inline short f2bf(float f) {
  union { float f; unsigned u; } a; a.f = f;
  unsigned r = a.u + 0x7FFF + ((a.u >> 16) & 1);   // RTN-even
  return (short)(r >> 16);
}
__device__ inline float bf2f(short b) {
  union { unsigned u; float f; } a; a.u = ((unsigned)(unsigned short)b) << 16;
  return a.f;
}

// ---------------------------------------------------------------------------
// Graph build
// ---------------------------------------------------------------------------
__global__ void count_deg_kernel(const int* __restrict__ dst, int* __restrict__ deg, int e) {
  int i = blockIdx.x * blockDim.x + threadIdx.x;
  int stride = gridDim.x * blockDim.x;
  for (; i < e; i += stride) atomicAdd(&deg[dst[i]], 1);
}

__global__ void dinv_kernel(const int* __restrict__ deg, float* __restrict__ dinv, int n) {
  int i = blockIdx.x * blockDim.x + threadIdx.x;
  if (i < n) dinv[i] = rsqrtf((float)deg[i] + 1.0f);
}

#define SCAN_T 1024
__global__ void scan_blocks_kernel(const int* __restrict__ deg, int* __restrict__ rs,
                                   int* __restrict__ bsum, int n) {
  __shared__ int s[SCAN_T];
  int t = threadIdx.x;
  int i = blockIdx.x * SCAN_T + t;
  int own = (i < n) ? deg[i] : 0;
  s[t] = own;
  for (int off = 1; off < SCAN_T; off <<= 1) {
    __syncthreads();
    int add = (t >= off) ? s[t - off] : 0;
    __syncthreads();
    s[t] += add;
  }
  if (i < n) rs[i] = s[t] - own;
  if (t == SCAN_T - 1) bsum[blockIdx.x] = s[t];
}

__global__ void scan_bsum_kernel(int* __restrict__ bsum, int nb) {
  __shared__ int s[128];
  int t = threadIdx.x;
  int v = (t < nb) ? bsum[t] : 0;
  s[t] = v;
  for (int off = 1; off < 128; off <<= 1) {
    __syncthreads();
    int add = (t >= off) ? s[t - off] : 0;
    __syncthreads();
    s[t] += add;
  }
  if (t < nb) bsum[t] = s[t] - v;
}

__global__ void add_off_kernel(int* __restrict__ rs, const int* __restrict__ bsum, int n) {
  int i = blockIdx.x * blockDim.x + threadIdx.x;
  if (i < n) rs[i] += bsum[i >> 10];
}

__global__ void fill_csr_kernel(const int* __restrict__ src, const int* __restrict__ dst,
                                const int* __restrict__ rs, int* __restrict__ cursor,
                                int* __restrict__ col, int e) {
  int i = blockIdx.x * blockDim.x + threadIdx.x;
  int stride = gridDim.x * blockDim.x;
  for (; i < e; i += stride) {
    int d = dst[i];
    int p = rs[d] + atomicAdd(&cursor[d], 1);
    col[p] = src[i];
  }
}

// ---------------------------------------------------------------------------
// Weight convert + transpose: W[K][N] f32 -> Wt[N][K] bf16
// ---------------------------------------------------------------------------
__global__ void convert_wt_kernel(const float* __restrict__ W, short* __restrict__ Wt,
                                  int K, int N) {
  int i = blockIdx.x * blockDim.x + threadIdx.x;
  if (i < K * N) {
    int k = i / N, nn = i - k * N;
    Wt[nn * K + k] = f2bf(W[i]);
  }
}

// ---------------------------------------------------------------------------
// MFMA GEMM: G[r, 0:256] = bf16( (A[r, :K] @ W[:K, 0:256]) * dinv[r] )
// A: f32 (AF32) or bf16 row-major [n][K].  Wt: bf16 [256][K] (B^T).
// Block: 256 thr (4 waves, 1x4), tile BM=64 x BN=256, BK=64.
// LDS XOR-swizzle (16B units) for conflict-free ds_read_b128.
// mfma_f32_16x16x32_bf16: A lane l -> row l&15, k=8*(l>>4)+j (contig);
//                          B lane l -> col l&15, k=8*(l>>4)+j;
//                          C lane l reg j -> col l&15, row (l>>4)*4+j.
// ---------------------------------------------------------------------------
template <int K, bool AF32>
__global__ __launch_bounds__(256, 3) void gemm_mfma_kernel(
    const void* __restrict__ Aptr, const short* __restrict__ Wt,
    const float* __restrict__ dinv, short* __restrict__ G, int n) {
  __shared__ short As[64 * 64];    // 8 KB
  __shared__ short Bs[256 * 64];   // 32 KB
  int tid = threadIdx.x;
  int lane = tid & 63, wid = tid >> 6;
  int wn = wid;                    // wave col 0..3
  int l15 = lane & 15, lh = lane >> 4;
  int rowBase = blockIdx.x * 64;

  f32x4 acc[4][4];
#pragma unroll
  for (int mi = 0; mi < 4; mi++)
#pragma unroll
    for (int ni = 0; ni < 4; ni++) acc[mi][ni] = (f32x4){0.f, 0.f, 0.f, 0.f};

  for (int kt = 0; kt < K; kt += 64) {
    // stage A: 64 rows x 8 16B-units = 512 units, 2 per thread
#pragma unroll
    for (int i = 0; i < 2; i++) {
      int s = tid + i * 256;
      int r = s >> 3, u = s & 7;
      int gr = rowBase + r; if (gr >= n) gr = n - 1;
      short8v v;
      if constexpr (AF32) {
        const float* ap = (const float*)Aptr + (size_t)gr * K + kt + u * 8;
        float4 f0 = *(const float4*)ap;
        float4 f1 = *(const float4*)(ap + 4);
        v[0] = f2bf(f0.x); v[1] = f2bf(f0.y); v[2] = f2bf(f0.z); v[3] = f2bf(f0.w);
        v[4] = f2bf(f1.x); v[5] = f2bf(f1.y); v[6] = f2bf(f1.z); v[7] = f2bf(f1.w);
      } else {
        v = *(const short8v*)((const short*)Aptr + (size_t)gr * K + kt + u * 8);
      }
      *(short8v*)&As[r * 64 + ((u ^ (r & 7)) << 3)] = v;
    }
    // stage B: 256 rows x 8 units = 2048 units, 8 per thread
#pragma unroll
    for (int i = 0; i < 8; i++) {
      int s = tid + i * 256;
      int r = s >> 3, u = s & 7;
      short8v v = *(const short8v*)(Wt + (size_t)r * K + kt + u * 8);
      *(short8v*)&Bs[r * 64 + ((u ^ (r & 7)) << 3)] = v;
    }
    __syncthreads();
#pragma unroll
    for (int kk = 0; kk < 2; kk++) {
      int u = kk * 4 + lh;
      short8v af[4], bf[4];
#pragma unroll
      for (int mi = 0; mi < 4; mi++) {
        int r = mi * 16 + l15;
        af[mi] = *(const short8v*)&As[r * 64 + ((u ^ (r & 7)) << 3)];
      }
#pragma unroll
      for (int ni = 0; ni < 4; ni++) {
        int r = wn * 64 + ni * 16 + l15;
        bf[ni] = *(const short8v*)&Bs[r * 64 + ((u ^ (r & 7)) << 3)];
      }
#pragma unroll
      for (int mi = 0; mi < 4; mi++)
#pragma unroll
        for (int ni = 0; ni < 4; ni++)
          acc[mi][ni] = __builtin_amdgcn_mfma_f32_16x16x32_bf16(
              af[mi], bf[ni], acc[mi][ni], 0, 0, 0);
    }
    __syncthreads();
  }

  // epilogue: scale by dinv[row], cvt bf16, store
#pragma unroll
  for (int mi = 0; mi < 4; mi++) {
#pragma unroll
    for (int j = 0; j < 4; j++) {
      int gr = rowBase + mi * 16 + lh * 4 + j;
      if (gr < n) {
        float sc = dinv[gr];
#pragma unroll
        for (int ni = 0; ni < 4; ni++) {
          int gc = wn * 64 + ni * 16 + l15;
          G[(size_t)gr * 256 + gc] = f2bf(acc[mi][ni][j] * sc);
        }
      }
    }
  }
}

// ---------------------------------------------------------------------------
// Aggregate 256-dim from bf16 G, f32 accumulate.
// H[v] = relu?( dinv[v]*(sum_{u->v} G[u] + G[v]) + bias )
// Writes bf16 Hb always; f32 Hf if WF32.
// ---------------------------------------------------------------------------
template <int RELU, int WF32>
__global__ __launch_bounds__(256) void aggregate_bf16_kernel(
    const short* __restrict__ G, const int* __restrict__ col,
    const int* __restrict__ rs, const int* __restrict__ deg,
    const float* __restrict__ dinv, const float* __restrict__ bias,
    short* __restrict__ Hb, float* __restrict__ Hf, int n) {
  int wid = threadIdx.x >> 6;
  int lane = threadIdx.x & 63;
  int v = blockIdx.x * 4 + wid;
  if (v >= n) return;
  short4v g = *(const short4v*)(G + (size_t)v * 256 + lane * 4);
  float a0 = bf2f(g[0]), a1 = bf2f(g[1]), a2 = bf2f(g[2]), a3 = bf2f(g[3]);
  int base = rs[v], cnt = deg[v];
  for (int i = 0; i < cnt; i++) {
    int u = col[base + i];
    short4v m = *(const short4v*)(G + (size_t)u * 256 + lane * 4);
    a0 += bf2f(m[0]); a1 += bf2f(m[1]); a2 += bf2f(m[2]); a3 += bf2f(m[3]);
  }
  float s = dinv[v];
  float4 b4 = ((const float4*)bias)[lane];
  float o0 = a0 * s + b4.x, o1 = a1 * s + b4.y, o2 = a2 * s + b4.z, o3 = a3 * s + b4.w;
  if (RELU) {
    o0 = fmaxf(o0, 0.f); o1 = fmaxf(o1, 0.f);
    o2 = fmaxf(o2, 0.f); o3 = fmaxf(o3, 0.f);
  }
  short4v ob; ob[0] = f2bf(o0); ob[1] = f2bf(o1); ob[2] = f2bf(o2); ob[3] = f2bf(o3);
  *(short4v*)(Hb + (size_t)v * 256 + lane * 4) = ob;
  if (WF32) {
    float4 of; of.x = o0; of.y = o1; of.z = o2; of.w = o3;
    *(float4*)(Hf + (size_t)v * 256 + lane * 4) = of;
  }
}

// ---------------------------------------------------------------------------
// Final GEMM (K=256 bf16 in, M=40 f32 out): wave per row, W2 f32 in LDS.
// ---------------------------------------------------------------------------
__global__ __launch_bounds__(256) void gemm40_kernel(
    const short* __restrict__ A, const float* __restrict__ W2,
    const float* __restrict__ dinv, float* __restrict__ G2, int n) {
  __shared__ float Ws[256 * 40];
  for (int i = threadIdx.x; i < 256 * 40; i += 256) Ws[i] = W2[i];
  __syncthreads();
  int wid = threadIdx.x >> 6;
  int lane = threadIdx.x & 63;
  int r = blockIdx.x * 4 + wid;
  if (r >= n) return;
  if (lane < 40) {
    const short* Ar = A + (size_t)r * 256;
    float acc = 0.f;
#pragma unroll 4
    for (int k = 0; k < 256; k += 8) {
      short8v a = *(const short8v*)(Ar + k);
#pragma unroll
      for (int j = 0; j < 8; j++) acc += bf2f(a[j]) * Ws[(k + j) * 40 + lane];
    }
    G2[(size_t)r * 40 + lane] = acc * dinv[r];
  }
}

// ---------------------------------------------------------------------------
// Aggregate 40-dim + bias + log_softmax.
// ---------------------------------------------------------------------------
__global__ __launch_bounds__(256) void agg40_lsm_kernel(
    const float* __restrict__ G2, const int* __restrict__ col,
    const int* __restrict__ rs, const int* __restrict__ deg,
    const float* __restrict__ dinv, const float* __restrict__ b2,
    float* __restrict__ out, int n) {
  int wid = threadIdx.x >> 6;
  int lane = threadIdx.x & 63;
  int v = blockIdx.x * 4 + wid;
  if (v >= n) return;
  bool act = lane < 40;
  float acc = 0.f;
  if (act) acc = G2[(size_t)v * 40 + lane];
  int base = rs[v], cnt = deg[v];
  for (int i = 0; i < cnt; i++) {
    int u = col[base + i];
    if (act) acc += G2[(size_t)u * 40 + lane];
  }
  float val;
  if (act) val = acc * dinv[v] + b2[lane];
  else val = -INFINITY;
  float m = val;
  for (int off = 32; off; off >>= 1) m = fmaxf(m, __shfl_xor(m, off, 64));
  float e = act ? expf(val - m) : 0.f;
  float ssum = e;
  for (int off = 32; off; off >>= 1) ssum += __shfl_xor(ssum, off, 64);
  if (act) out[(size_t)v * 40 + lane] = val - m - logf(ssum);
}

// ---------------------------------------------------------------------------

static inline size_t alignup(size_t x) { return (x + 255) & ~(size_t)255; }

extern "C" void kernel_launch(void* const* d_in, const int* in_sizes, int n_in,
                              void* d_out, int out_size, void* d_ws, size_t ws_size,
                              hipStream_t stream) {
  const float* x  = (const float*)d_in[0];
  const int*   ei = (const int*)d_in[1];
  const float* W1 = (const float*)d_in[2];
  const float* b1 = (const float*)d_in[3];
  const float* Wi = (const float*)d_in[4];
  const float* bi = (const float*)d_in[5];
  const float* W2 = (const float*)d_in[6];
  const float* b2 = (const float*)d_in[7];

  const int in_d = 512, mid_d = 256, out_d = 40;
  int n = in_sizes[0] / in_d;       // 100000
  int E = in_sizes[1] / 2;          // 1600000
  const int* src = ei;
  const int* dst = ei + E;

  float* out_lsm = (float*)d_out;                        // n*40
  float* emb     = (float*)d_out + (size_t)n * out_d;    // n*256

  // workspace layout (~111 MB)
  char* w = (char*)d_ws;
  float* dinv  = (float*)w;  w += alignup((size_t)n * 4);
  int* deg     = (int*)w;    w += alignup((size_t)n * 4);
  int* rs      = (int*)w;    w += alignup((size_t)n * 4);
  int* cursor  = (int*)w;    w += alignup((size_t)n * 4);
  int* colidx  = (int*)w;    w += alignup((size_t)E * 4);
  int* bsum    = (int*)w;    w += alignup(128 * 4);
  short* W1t   = (short*)w;  w += alignup((size_t)mid_d * in_d * 2);   // [256][512]
  short* Wit   = (short*)w;  w += alignup((size_t)mid_d * mid_d * 2);  // [256][256]
  short* Gb    = (short*)w;  w += alignup((size_t)n * mid_d * 2);      // bf16 g
  short* Hb    = (short*)w;  w += alignup((size_t)n * mid_d * 2);      // bf16 h
  float* G2    = (float*)Gb;   // alias: Gb is dead when gemm40 runs

  int nb = (n + SCAN_T - 1) / SCAN_T;

  // --- graph build ---
  hipMemsetAsync(deg, 0, (size_t)n * 4, stream);
  hipMemsetAsync(cursor, 0, (size_t)n * 4, stream);
  count_deg_kernel<<<2048, 256, 0, stream>>>(dst, deg, E);
  dinv_kernel<<<(n + 255) / 256, 256, 0, stream>>>(deg, dinv, n);
  scan_blocks_kernel<<<nb, SCAN_T, 0, stream>>>(deg, rs, bsum, n);
  scan_bsum_kernel<<<1, 128, 0, stream>>>(bsum, nb);
  add_off_kernel<<<(n + 255) / 256, 256, 0, stream>>>(rs, bsum, n);
  fill_csr_kernel<<<2048, 256, 0, stream>>>(src, dst, rs, cursor, colidx, E);

  // --- weights -> bf16 transposed ---
  convert_wt_kernel<<<(in_d * mid_d + 255) / 256, 256, 0, stream>>>(W1, W1t, in_d, mid_d);
  convert_wt_kernel<<<(mid_d * mid_d + 255) / 256, 256, 0, stream>>>(Wi, Wit, mid_d, mid_d);

  int ggrid = (n + 63) / 64;        // 1563
  int agg_grid = (n + 3) / 4;

  // --- conv1: x(512,f32) -> h(256), bias b1, no relu ---
  gemm_mfma_kernel<512, true><<<ggrid, 256, 0, stream>>>(x, W1t, dinv, Gb, n);
  aggregate_bf16_kernel<0, 0><<<agg_grid, 256, 0, stream>>>(
      Gb, colidx, rs, deg, dinv, b1, Hb, nullptr, n);

  // --- conv2..3: relu, bf16 only ---
  for (int l = 0; l < 2; l++) {
    gemm_mfma_kernel<256, false><<<ggrid, 256, 0, stream>>>(Hb, Wit, dinv, Gb, n);
    aggregate_bf16_kernel<1, 0><<<agg_grid, 256, 0, stream>>>(
        Gb, colidx, rs, deg, dinv, bi, Hb, nullptr, n);
  }
  // --- conv4: relu, also write f32 emb ---
  gemm_mfma_kernel<256, false><<<ggrid, 256, 0, stream>>>(Hb, Wit, dinv, Gb, n);
  aggregate_bf16_kernel<1, 1><<<agg_grid, 256, 0, stream>>>(
      Gb, colidx, rs, deg, dinv, bi, Hb, emb, n);

  // --- conv5: h(256,bf16) -> 40, bias b2, log_softmax ---
  gemm40_kernel<<<agg_grid, 256, 0, stream>>>(Hb, W2, dinv, G2, n);
  agg40_lsm_kernel<<<agg_grid, 256, 0, stream>>>(G2, colidx, rs, deg, dinv, b2, out_lsm, n);
}

// Round 3
// 932.373 us; speedup vs baseline: 2.5542x; 1.4872x over previous
//
#include <hip/hip_runtime.h>
#include <cmath>

typedef __attribute__((ext_vector_type(8))) short short8v;
typedef __attribute__((ext_vector_type(4))) short short4v;
typedef __attribute__((ext_vector_type(4))) float f32x4;

__device__ inline short f2bf(float f) {
  union { float f; unsigned u; } a; a.f = f;
  unsigned r = a.u + 0x7FFF + ((a.u >> 16) & 1);   // RTN-even
  return (short)(r >> 16);
}
__device__ inline float bf2f(short b) {
  union { unsigned u; float f; } a; a.u = ((unsigned)(unsigned short)b) << 16;
  return a.f;
}

// ---------------------------------------------------------------------------
// Graph build
// ---------------------------------------------------------------------------
__global__ void count_deg_kernel(const int* __restrict__ dst, int* __restrict__ deg, int e) {
  int i = blockIdx.x * blockDim.x + threadIdx.x;
  int stride = gridDim.x * blockDim.x;
  for (; i < e; i += stride) atomicAdd(&deg[dst[i]], 1);
}

__global__ void dinv_kernel(const int* __restrict__ deg, float* __restrict__ dinv, int n) {
  int i = blockIdx.x * blockDim.x + threadIdx.x;
  if (i < n) dinv[i] = rsqrtf((float)deg[i] + 1.0f);
}

#define SCAN_T 1024
__global__ void scan_blocks_kernel(const int* __restrict__ deg, int* __restrict__ rs,
                                   int* __restrict__ bsum, int n) {
  __shared__ int s[SCAN_T];
  int t = threadIdx.x;
  int i = blockIdx.x * SCAN_T + t;
  int own = (i < n) ? deg[i] : 0;
  s[t] = own;
  for (int off = 1; off < SCAN_T; off <<= 1) {
    __syncthreads();
    int add = (t >= off) ? s[t - off] : 0;
    __syncthreads();
    s[t] += add;
  }
  if (i < n) rs[i] = s[t] - own;
  if (t == SCAN_T - 1) bsum[blockIdx.x] = s[t];
}

__global__ void scan_bsum_kernel(int* __restrict__ bsum, int nb) {
  __shared__ int s[128];
  int t = threadIdx.x;
  int v = (t < nb) ? bsum[t] : 0;
  s[t] = v;
  for (int off = 1; off < 128; off <<= 1) {
    __syncthreads();
    int add = (t >= off) ? s[t - off] : 0;
    __syncthreads();
    s[t] += add;
  }
  if (t < nb) bsum[t] = s[t] - v;
}

__global__ void add_off_kernel(int* __restrict__ rs, const int* __restrict__ bsum, int n) {
  int i = blockIdx.x * blockDim.x + threadIdx.x;
  if (i < n) rs[i] += bsum[i >> 10];
}

__global__ void fill_csr_kernel(const int* __restrict__ src, const int* __restrict__ dst,
                                const int* __restrict__ rs, int* __restrict__ cursor,
                                int* __restrict__ col, int e) {
  int i = blockIdx.x * blockDim.x + threadIdx.x;
  int stride = gridDim.x * blockDim.x;
  for (; i < e; i += stride) {
    int d = dst[i];
    int p = rs[d] + atomicAdd(&cursor[d], 1);
    col[p] = src[i];
  }
}

// ---------------------------------------------------------------------------
// Weight converts
// ---------------------------------------------------------------------------
__global__ void convert_wt_kernel(const float* __restrict__ W, short* __restrict__ Wt,
                                  int K, int N) {
  int i = blockIdx.x * blockDim.x + threadIdx.x;
  if (i < K * N) {
    int k = i / N, nn = i - k * N;
    Wt[nn * K + k] = f2bf(W[i]);
  }
}

// W2 [256][40] f32 -> W2t [64][256] bf16, zero-padded cols 40..63
__global__ void convert_w2t_kernel(const float* __restrict__ W2, short* __restrict__ W2t) {
  int i = blockIdx.x * blockDim.x + threadIdx.x;
  if (i < 64 * 256) {
    int c = i >> 8, k = i & 255;
    W2t[i] = (c < 40) ? f2bf(W2[k * 40 + c]) : (short)0;
  }
}

// ---------------------------------------------------------------------------
// MFMA GEMM: G[r, 0:256] = bf16( (A[r, :K] @ W[:K, 0:256]) * dinv[r] )
// BM=64 x BN=256 (wave per 64-col slab), BK=64, XOR-swizzled LDS.
// ---------------------------------------------------------------------------
template <int K, bool AF32>
__global__ __launch_bounds__(256, 3) void gemm_mfma_kernel(
    const void* __restrict__ Aptr, const short* __restrict__ Wt,
    const float* __restrict__ dinv, short* __restrict__ G, int n) {
  __shared__ short As[64 * 64];    // 8 KB
  __shared__ short Bs[256 * 64];   // 32 KB
  int tid = threadIdx.x;
  int lane = tid & 63, wid = tid >> 6;
  int wn = wid;
  int l15 = lane & 15, lh = lane >> 4;
  int rowBase = blockIdx.x * 64;

  f32x4 acc[4][4];
#pragma unroll
  for (int mi = 0; mi < 4; mi++)
#pragma unroll
    for (int ni = 0; ni < 4; ni++) acc[mi][ni] = (f32x4){0.f, 0.f, 0.f, 0.f};

  for (int kt = 0; kt < K; kt += 64) {
#pragma unroll
    for (int i = 0; i < 2; i++) {
      int s = tid + i * 256;
      int r = s >> 3, u = s & 7;
      int gr = rowBase + r; if (gr >= n) gr = n - 1;
      short8v v;
      if constexpr (AF32) {
        const float* ap = (const float*)Aptr + (size_t)gr * K + kt + u * 8;
        float4 f0 = *(const float4*)ap;
        float4 f1 = *(const float4*)(ap + 4);
        v[0] = f2bf(f0.x); v[1] = f2bf(f0.y); v[2] = f2bf(f0.z); v[3] = f2bf(f0.w);
        v[4] = f2bf(f1.x); v[5] = f2bf(f1.y); v[6] = f2bf(f1.z); v[7] = f2bf(f1.w);
      } else {
        v = *(const short8v*)((const short*)Aptr + (size_t)gr * K + kt + u * 8);
      }
      *(short8v*)&As[r * 64 + ((u ^ (r & 7)) << 3)] = v;
    }
#pragma unroll
    for (int i = 0; i < 8; i++) {
      int s = tid + i * 256;
      int r = s >> 3, u = s & 7;
      short8v v = *(const short8v*)(Wt + (size_t)r * K + kt + u * 8);
      *(short8v*)&Bs[r * 64 + ((u ^ (r & 7)) << 3)] = v;
    }
    __syncthreads();
#pragma unroll
    for (int kk = 0; kk < 2; kk++) {
      int u = kk * 4 + lh;
      short8v af[4], bf[4];
#pragma unroll
      for (int mi = 0; mi < 4; mi++) {
        int r = mi * 16 + l15;
        af[mi] = *(const short8v*)&As[r * 64 + ((u ^ (r & 7)) << 3)];
      }
#pragma unroll
      for (int ni = 0; ni < 4; ni++) {
        int r = wn * 64 + ni * 16 + l15;
        bf[ni] = *(const short8v*)&Bs[r * 64 + ((u ^ (r & 7)) << 3)];
      }
#pragma unroll
      for (int mi = 0; mi < 4; mi++)
#pragma unroll
        for (int ni = 0; ni < 4; ni++)
          acc[mi][ni] = __builtin_amdgcn_mfma_f32_16x16x32_bf16(
              af[mi], bf[ni], acc[mi][ni], 0, 0, 0);
    }
    __syncthreads();
  }

#pragma unroll
  for (int mi = 0; mi < 4; mi++) {
#pragma unroll
    for (int j = 0; j < 4; j++) {
      int gr = rowBase + mi * 16 + lh * 4 + j;
      if (gr < n) {
        float sc = dinv[gr];
#pragma unroll
        for (int ni = 0; ni < 4; ni++) {
          int gc = wn * 64 + ni * 16 + l15;
          G[(size_t)gr * 256 + gc] = f2bf(acc[mi][ni][j] * sc);
        }
      }
    }
  }
}

// ---------------------------------------------------------------------------
// Final MFMA GEMM: G2[r, 0:40] = f32( (Hb[r,:256] @ W2[:256,0:40]) * dinv[r] )
// BM=256 rows/block (wave per 64-row slab), BN=64 (40 real + 24 pad), BK=64.
// ---------------------------------------------------------------------------
__global__ __launch_bounds__(256, 3) void gemm_mfma40_kernel(
    const short* __restrict__ Hb, const short* __restrict__ W2t,
    const float* __restrict__ dinv, float* __restrict__ G2, int n) {
  __shared__ short As[256 * 64];   // 32 KB
  __shared__ short Bs[64 * 64];    // 8 KB
  int tid = threadIdx.x;
  int lane = tid & 63, wid = tid >> 6;
  int l15 = lane & 15, lh = lane >> 4;
  int rowBase = blockIdx.x * 256;

  f32x4 acc[4][4];
#pragma unroll
  for (int mi = 0; mi < 4; mi++)
#pragma unroll
    for (int ni = 0; ni < 4; ni++) acc[mi][ni] = (f32x4){0.f, 0.f, 0.f, 0.f};

  for (int kt = 0; kt < 256; kt += 64) {
#pragma unroll
    for (int i = 0; i < 8; i++) {
      int s = tid + i * 256;
      int r = s >> 3, u = s & 7;
      int gr = rowBase + r; if (gr >= n) gr = n - 1;
      short8v v = *(const short8v*)(Hb + (size_t)gr * 256 + kt + u * 8);
      *(short8v*)&As[r * 64 + ((u ^ (r & 7)) << 3)] = v;
    }
#pragma unroll
    for (int i = 0; i < 2; i++) {
      int s = tid + i * 256;
      int r = s >> 3, u = s & 7;
      short8v v = *(const short8v*)(W2t + (size_t)r * 256 + kt + u * 8);
      *(short8v*)&Bs[r * 64 + ((u ^ (r & 7)) << 3)] = v;
    }
    __syncthreads();
#pragma unroll
    for (int kk = 0; kk < 2; kk++) {
      int u = kk * 4 + lh;
      short8v af[4], bf[4];
#pragma unroll
      for (int mi = 0; mi < 4; mi++) {
        int r = wid * 64 + mi * 16 + l15;
        af[mi] = *(const short8v*)&As[r * 64 + ((u ^ (r & 7)) << 3)];
      }
#pragma unroll
      for (int ni = 0; ni < 4; ni++) {
        int r = ni * 16 + l15;
        bf[ni] = *(const short8v*)&Bs[r * 64 + ((u ^ (r & 7)) << 3)];
      }
#pragma unroll
      for (int mi = 0; mi < 4; mi++)
#pragma unroll
        for (int ni = 0; ni < 4; ni++)
          acc[mi][ni] = __builtin_amdgcn_mfma_f32_16x16x32_bf16(
              af[mi], bf[ni], acc[mi][ni], 0, 0, 0);
    }
    __syncthreads();
  }

#pragma unroll
  for (int mi = 0; mi < 4; mi++) {
#pragma unroll
    for (int j = 0; j < 4; j++) {
      int gr = rowBase + wid * 64 + mi * 16 + lh * 4 + j;
      if (gr < n) {
        float sc = dinv[gr];
#pragma unroll
        for (int ni = 0; ni < 4; ni++) {
          int gc = ni * 16 + l15;
          if (gc < 40) G2[(size_t)gr * 40 + gc] = acc[mi][ni][j] * sc;
        }
      }
    }
  }
}

// ---------------------------------------------------------------------------
// Aggregate 256-dim from bf16 G, f32 accumulate, 4x-unrolled gather.
// ---------------------------------------------------------------------------
template <int RELU, int WF32>
__global__ __launch_bounds__(256) void aggregate_bf16_kernel(
    const short* __restrict__ G, const int* __restrict__ col,
    const int* __restrict__ rs, const int* __restrict__ deg,
    const float* __restrict__ dinv, const float* __restrict__ bias,
    short* __restrict__ Hb, float* __restrict__ Hf, int n) {
  int wid = threadIdx.x >> 6;
  int lane = threadIdx.x & 63;
  int v = blockIdx.x * 4 + wid;
  if (v >= n) return;
  short4v g = *(const short4v*)(G + (size_t)v * 256 + lane * 4);
  float a0 = bf2f(g[0]), a1 = bf2f(g[1]), a2 = bf2f(g[2]), a3 = bf2f(g[3]);
  int base = rs[v], cnt = deg[v];
  int i = 0;
  for (; i + 4 <= cnt; i += 4) {
    int u0 = col[base + i], u1 = col[base + i + 1];
    int u2 = col[base + i + 2], u3 = col[base + i + 3];
    short4v m0 = *(const short4v*)(G + (size_t)u0 * 256 + lane * 4);
    short4v m1 = *(const short4v*)(G + (size_t)u1 * 256 + lane * 4);
    short4v m2 = *(const short4v*)(G + (size_t)u2 * 256 + lane * 4);
    short4v m3 = *(const short4v*)(G + (size_t)u3 * 256 + lane * 4);
    a0 += bf2f(m0[0]) + bf2f(m1[0]) + bf2f(m2[0]) + bf2f(m3[0]);
    a1 += bf2f(m0[1]) + bf2f(m1[1]) + bf2f(m2[1]) + bf2f(m3[1]);
    a2 += bf2f(m0[2]) + bf2f(m1[2]) + bf2f(m2[2]) + bf2f(m3[2]);
    a3 += bf2f(m0[3]) + bf2f(m1[3]) + bf2f(m2[3]) + bf2f(m3[3]);
  }
  for (; i < cnt; i++) {
    int u = col[base + i];
    short4v m = *(const short4v*)(G + (size_t)u * 256 + lane * 4);
    a0 += bf2f(m[0]); a1 += bf2f(m[1]); a2 += bf2f(m[2]); a3 += bf2f(m[3]);
  }
  float s = dinv[v];
  float4 b4 = ((const float4*)bias)[lane];
  float o0 = a0 * s + b4.x, o1 = a1 * s + b4.y, o2 = a2 * s + b4.z, o3 = a3 * s + b4.w;
  if (RELU) {
    o0 = fmaxf(o0, 0.f); o1 = fmaxf(o1, 0.f);
    o2 = fmaxf(o2, 0.f); o3 = fmaxf(o3, 0.f);
  }
  short4v ob; ob[0] = f2bf(o0); ob[1] = f2bf(o1); ob[2] = f2bf(o2); ob[3] = f2bf(o3);
  *(short4v*)(Hb + (size_t)v * 256 + lane * 4) = ob;
  if (WF32) {
    float4 of; of.x = o0; of.y = o1; of.z = o2; of.w = o3;
    *(float4*)(Hf + (size_t)v * 256 + lane * 4) = of;
  }
}

// ---------------------------------------------------------------------------
// Aggregate 40-dim + bias + log_softmax, 4x-unrolled gather.
// ---------------------------------------------------------------------------
__global__ __launch_bounds__(256) void agg40_lsm_kernel(
    const float* __restrict__ G2, const int* __restrict__ col,
    const int* __restrict__ rs, const int* __restrict__ deg,
    const float* __restrict__ dinv, const float* __restrict__ b2,
    float* __restrict__ out, int n) {
  int wid = threadIdx.x >> 6;
  int lane = threadIdx.x & 63;
  int v = blockIdx.x * 4 + wid;
  if (v >= n) return;
  bool act = lane < 40;
  int ln = act ? lane : 0;
  float acc = act ? G2[(size_t)v * 40 + lane] : 0.f;
  int base = rs[v], cnt = deg[v];
  int i = 0;
  for (; i + 4 <= cnt; i += 4) {
    int u0 = col[base + i], u1 = col[base + i + 1];
    int u2 = col[base + i + 2], u3 = col[base + i + 3];
    float x0 = G2[(size_t)u0 * 40 + ln];
    float x1 = G2[(size_t)u1 * 40 + ln];
    float x2 = G2[(size_t)u2 * 40 + ln];
    float x3 = G2[(size_t)u3 * 40 + ln];
    acc += x0 + x1 + x2 + x3;
  }
  for (; i < cnt; i++) {
    int u = col[base + i];
    acc += G2[(size_t)u * 40 + ln];
  }
  float val;
  if (act) val = acc * dinv[v] + b2[lane];
  else val = -INFINITY;
  float m = val;
  for (int off = 32; off; off >>= 1) m = fmaxf(m, __shfl_xor(m, off, 64));
  float e = act ? expf(val - m) : 0.f;
  float ssum = e;
  for (int off = 32; off; off >>= 1) ssum += __shfl_xor(ssum, off, 64);
  if (act) out[(size_t)v * 40 + lane] = val - m - logf(ssum);
}

// ---------------------------------------------------------------------------

static inline size_t alignup(size_t x) { return (x + 255) & ~(size_t)255; }

extern "C" void kernel_launch(void* const* d_in, const int* in_sizes, int n_in,
                              void* d_out, int out_size, void* d_ws, size_t ws_size,
                              hipStream_t stream) {
  const float* x  = (const float*)d_in[0];
  const int*   ei = (const int*)d_in[1];
  const float* W1 = (const float*)d_in[2];
  const float* b1 = (const float*)d_in[3];
  const float* Wi = (const float*)d_in[4];
  const float* bi = (const float*)d_in[5];
  const float* W2 = (const float*)d_in[6];
  const float* b2 = (const float*)d_in[7];

  const int in_d = 512, mid_d = 256, out_d = 40;
  int n = in_sizes[0] / in_d;       // 100000
  int E = in_sizes[1] / 2;          // 1600000
  const int* src = ei;
  const int* dst = ei + E;

  float* out_lsm = (float*)d_out;                        // n*40
  float* emb     = (float*)d_out + (size_t)n * out_d;    // n*256

  char* w = (char*)d_ws;
  float* dinv  = (float*)w;  w += alignup((size_t)n * 4);
  int* deg     = (int*)w;    w += alignup((size_t)n * 4);
  int* rs      = (int*)w;    w += alignup((size_t)n * 4);
  int* cursor  = (int*)w;    w += alignup((size_t)n * 4);
  int* colidx  = (int*)w;    w += alignup((size_t)E * 4);
  int* bsum    = (int*)w;    w += alignup(128 * 4);
  short* W1t   = (short*)w;  w += alignup((size_t)mid_d * in_d * 2);
  short* Wit   = (short*)w;  w += alignup((size_t)mid_d * mid_d * 2);
  short* W2t   = (short*)w;  w += alignup((size_t)64 * mid_d * 2);
  short* Gb    = (short*)w;  w += alignup((size_t)n * mid_d * 2);
  short* Hb    = (short*)w;  w += alignup((size_t)n * mid_d * 2);
  float* G2    = (float*)Gb;   // alias: Gb dead when final gemm runs

  int nb = (n + SCAN_T - 1) / SCAN_T;

  hipMemsetAsync(deg, 0, (size_t)n * 4, stream);
  hipMemsetAsync(cursor, 0, (size_t)n * 4, stream);
  count_deg_kernel<<<2048, 256, 0, stream>>>(dst, deg, E);
  dinv_kernel<<<(n + 255) / 256, 256, 0, stream>>>(deg, dinv, n);
  scan_blocks_kernel<<<nb, SCAN_T, 0, stream>>>(deg, rs, bsum, n);
  scan_bsum_kernel<<<1, 128, 0, stream>>>(bsum, nb);
  add_off_kernel<<<(n + 255) / 256, 256, 0, stream>>>(rs, bsum, n);
  fill_csr_kernel<<<2048, 256, 0, stream>>>(src, dst, rs, cursor, colidx, E);

  convert_wt_kernel<<<(in_d * mid_d + 255) / 256, 256, 0, stream>>>(W1, W1t, in_d, mid_d);
  convert_wt_kernel<<<(mid_d * mid_d + 255) / 256, 256, 0, stream>>>(Wi, Wit, mid_d, mid_d);
  convert_w2t_kernel<<<(64 * mid_d + 255) / 256, 256, 0, stream>>>(W2, W2t);

  int ggrid = (n + 63) / 64;
  int agg_grid = (n + 3) / 4;

  // conv1
  gemm_mfma_kernel<512, true><<<ggrid, 256, 0, stream>>>(x, W1t, dinv, Gb, n);
  aggregate_bf16_kernel<0, 0><<<agg_grid, 256, 0, stream>>>(
      Gb, colidx, rs, deg, dinv, b1, Hb, nullptr, n);
  // conv2..3
  for (int l = 0; l < 2; l++) {
    gemm_mfma_kernel<256, false><<<ggrid, 256, 0, stream>>>(Hb, Wit, dinv, Gb, n);
    aggregate_bf16_kernel<1, 0><<<agg_grid, 256, 0, stream>>>(
        Gb, colidx, rs, deg, dinv, bi, Hb, nullptr, n);
  }
  // conv4 (+ f32 emb)
  gemm_mfma_kernel<256, false><<<ggrid, 256, 0, stream>>>(Hb, Wit, dinv, Gb, n);
  aggregate_bf16_kernel<1, 1><<<agg_grid, 256, 0, stream>>>(
      Gb, colidx, rs, deg, dinv, bi, Hb, emb, n);

  // conv5: MFMA projection + lsm aggregate
  gemm_mfma40_kernel<<<(n + 255) / 256, 256, 0, stream>>>(Hb, W2t, dinv, G2, n);
  agg40_lsm_kernel<<<agg_grid, 256, 0, stream>>>(G2, colidx, rs, deg, dinv, b2, out_lsm, n);
}

// Round 4
// 917.314 us; speedup vs baseline: 2.5961x; 1.0164x over previous
//
#include <hip/hip_runtime.h>
#include <cmath>

typedef __attribute__((ext_vector_type(8))) short short8v;
typedef __attribute__((ext_vector_type(4))) short short4v;
typedef __attribute__((ext_vector_type(4))) float f32x4;

__device__ inline short f2bf(float f) {
  union { float f; unsigned u; } a; a.f = f;
  unsigned r = a.u + 0x7FFF + ((a.u >> 16) & 1);   // RTN-even
  return (short)(r >> 16);
}
__device__ inline float bf2f(short b) {
  union { unsigned u; float f; } a; a.u = ((unsigned)(unsigned short)b) << 16;
  return a.f;
}

// ---------------------------------------------------------------------------
// Graph build
// ---------------------------------------------------------------------------
__global__ void count_deg_kernel(const int* __restrict__ dst, int* __restrict__ deg, int e) {
  int i = blockIdx.x * blockDim.x + threadIdx.x;
  int stride = gridDim.x * blockDim.x;
  for (; i < e; i += stride) atomicAdd(&deg[dst[i]], 1);
}

__global__ void dinv_kernel(const int* __restrict__ deg, float* __restrict__ dinv, int n) {
  int i = blockIdx.x * blockDim.x + threadIdx.x;
  if (i < n) dinv[i] = rsqrtf((float)deg[i] + 1.0f);
}

#define SCAN_T 1024
__global__ void scan_blocks_kernel(const int* __restrict__ deg, int* __restrict__ rs,
                                   int* __restrict__ bsum, int n) {
  __shared__ int s[SCAN_T];
  int t = threadIdx.x;
  int i = blockIdx.x * SCAN_T + t;
  int own = (i < n) ? deg[i] : 0;
  s[t] = own;
  for (int off = 1; off < SCAN_T; off <<= 1) {
    __syncthreads();
    int add = (t >= off) ? s[t - off] : 0;
    __syncthreads();
    s[t] += add;
  }
  if (i < n) rs[i] = s[t] - own;
  if (t == SCAN_T - 1) bsum[blockIdx.x] = s[t];
}

__global__ void scan_bsum_kernel(int* __restrict__ bsum, int nb) {
  __shared__ int s[128];
  int t = threadIdx.x;
  int v = (t < nb) ? bsum[t] : 0;
  s[t] = v;
  for (int off = 1; off < 128; off <<= 1) {
    __syncthreads();
    int add = (t >= off) ? s[t - off] : 0;
    __syncthreads();
    s[t] += add;
  }
  if (t < nb) bsum[t] = s[t] - v;
}

__global__ void add_off_kernel(int* __restrict__ rs, const int* __restrict__ bsum, int n) {
  int i = blockIdx.x * blockDim.x + threadIdx.x;
  if (i < n) rs[i] += bsum[i >> 10];
}

__global__ void fill_csr_kernel(const int* __restrict__ src, const int* __restrict__ dst,
                                const int* __restrict__ rs, int* __restrict__ cursor,
                                int* __restrict__ col, int e) {
  int i = blockIdx.x * blockDim.x + threadIdx.x;
  int stride = gridDim.x * blockDim.x;
  for (; i < e; i += stride) {
    int d = dst[i];
    int p = rs[d] + atomicAdd(&cursor[d], 1);
    col[p] = src[i];
  }
}

// ---------------------------------------------------------------------------
// Weight converts
// ---------------------------------------------------------------------------
__global__ void convert_wt_kernel(const float* __restrict__ W, short* __restrict__ Wt,
                                  int K, int N) {
  int i = blockIdx.x * blockDim.x + threadIdx.x;
  if (i < K * N) {
    int k = i / N, nn = i - k * N;
    Wt[nn * K + k] = f2bf(W[i]);
  }
}

// W2 [256][40] f32 -> W2t [64][256] bf16, zero-padded cols 40..63
__global__ void convert_w2t_kernel(const float* __restrict__ W2, short* __restrict__ W2t) {
  int i = blockIdx.x * blockDim.x + threadIdx.x;
  if (i < 64 * 256) {
    int c = i >> 8, k = i & 255;
    W2t[i] = (c < 40) ? f2bf(W2[k * 40 + c]) : (short)0;
  }
}

// ---------------------------------------------------------------------------
// MFMA GEMM: G[r, 0:256] = bf16( (A[r, :K] @ W[:K, 0:256]) * dinv[r] )
// BM=64 x BN=256 (wave per 64-col slab), BK=64, XOR-swizzled LDS.
// ---------------------------------------------------------------------------
template <int K, bool AF32>
__global__ __launch_bounds__(256, 3) void gemm_mfma_kernel(
    const void* __restrict__ Aptr, const short* __restrict__ Wt,
    const float* __restrict__ dinv, short* __restrict__ G, int n) {
  __shared__ short As[64 * 64];    // 8 KB
  __shared__ short Bs[256 * 64];   // 32 KB
  int tid = threadIdx.x;
  int lane = tid & 63, wid = tid >> 6;
  int wn = wid;
  int l15 = lane & 15, lh = lane >> 4;
  int rowBase = blockIdx.x * 64;

  f32x4 acc[4][4];
#pragma unroll
  for (int mi = 0; mi < 4; mi++)
#pragma unroll
    for (int ni = 0; ni < 4; ni++) acc[mi][ni] = (f32x4){0.f, 0.f, 0.f, 0.f};

  for (int kt = 0; kt < K; kt += 64) {
#pragma unroll
    for (int i = 0; i < 2; i++) {
      int s = tid + i * 256;
      int r = s >> 3, u = s & 7;
      int gr = rowBase + r; if (gr >= n) gr = n - 1;
      short8v v;
      if constexpr (AF32) {
        const float* ap = (const float*)Aptr + (size_t)gr * K + kt + u * 8;
        float4 f0 = *(const float4*)ap;
        float4 f1 = *(const float4*)(ap + 4);
        v[0] = f2bf(f0.x); v[1] = f2bf(f0.y); v[2] = f2bf(f0.z); v[3] = f2bf(f0.w);
        v[4] = f2bf(f1.x); v[5] = f2bf(f1.y); v[6] = f2bf(f1.z); v[7] = f2bf(f1.w);
      } else {
        v = *(const short8v*)((const short*)Aptr + (size_t)gr * K + kt + u * 8);
      }
      *(short8v*)&As[r * 64 + ((u ^ (r & 7)) << 3)] = v;
    }
#pragma unroll
    for (int i = 0; i < 8; i++) {
      int s = tid + i * 256;
      int r = s >> 3, u = s & 7;
      short8v v = *(const short8v*)(Wt + (size_t)r * K + kt + u * 8);
      *(short8v*)&Bs[r * 64 + ((u ^ (r & 7)) << 3)] = v;
    }
    __syncthreads();
#pragma unroll
    for (int kk = 0; kk < 2; kk++) {
      int u = kk * 4 + lh;
      short8v af[4], bf[4];
#pragma unroll
      for (int mi = 0; mi < 4; mi++) {
        int r = mi * 16 + l15;
        af[mi] = *(const short8v*)&As[r * 64 + ((u ^ (r & 7)) << 3)];
      }
#pragma unroll
      for (int ni = 0; ni < 4; ni++) {
        int r = wn * 64 + ni * 16 + l15;
        bf[ni] = *(const short8v*)&Bs[r * 64 + ((u ^ (r & 7)) << 3)];
      }
#pragma unroll
      for (int mi = 0; mi < 4; mi++)
#pragma unroll
        for (int ni = 0; ni < 4; ni++)
          acc[mi][ni] = __builtin_amdgcn_mfma_f32_16x16x32_bf16(
              af[mi], bf[ni], acc[mi][ni], 0, 0, 0);
    }
    __syncthreads();
  }

#pragma unroll
  for (int mi = 0; mi < 4; mi++) {
#pragma unroll
    for (int j = 0; j < 4; j++) {
      int gr = rowBase + mi * 16 + lh * 4 + j;
      if (gr < n) {
        float sc = dinv[gr];
#pragma unroll
        for (int ni = 0; ni < 4; ni++) {
          int gc = wn * 64 + ni * 16 + l15;
          G[(size_t)gr * 256 + gc] = f2bf(acc[mi][ni][j] * sc);
        }
      }
    }
  }
}

// ---------------------------------------------------------------------------
// Final MFMA GEMM: G2[r, 0:40] = f32( (Hb[r,:256] @ W2[:256,0:40]) * dinv[r] )
// ---------------------------------------------------------------------------
__global__ __launch_bounds__(256, 3) void gemm_mfma40_kernel(
    const short* __restrict__ Hb, const short* __restrict__ W2t,
    const float* __restrict__ dinv, float* __restrict__ G2, int n) {
  __shared__ short As[256 * 64];   // 32 KB
  __shared__ short Bs[64 * 64];    // 8 KB
  int tid = threadIdx.x;
  int lane = tid & 63, wid = tid >> 6;
  int l15 = lane & 15, lh = lane >> 4;
  int rowBase = blockIdx.x * 256;

  f32x4 acc[4][4];
#pragma unroll
  for (int mi = 0; mi < 4; mi++)
#pragma unroll
    for (int ni = 0; ni < 4; ni++) acc[mi][ni] = (f32x4){0.f, 0.f, 0.f, 0.f};

  for (int kt = 0; kt < 256; kt += 64) {
#pragma unroll
    for (int i = 0; i < 8; i++) {
      int s = tid + i * 256;
      int r = s >> 3, u = s & 7;
      int gr = rowBase + r; if (gr >= n) gr = n - 1;
      short8v v = *(const short8v*)(Hb + (size_t)gr * 256 + kt + u * 8);
      *(short8v*)&As[r * 64 + ((u ^ (r & 7)) << 3)] = v;
    }
#pragma unroll
    for (int i = 0; i < 2; i++) {
      int s = tid + i * 256;
      int r = s >> 3, u = s & 7;
      short8v v = *(const short8v*)(W2t + (size_t)r * 256 + kt + u * 8);
      *(short8v*)&Bs[r * 64 + ((u ^ (r & 7)) << 3)] = v;
    }
    __syncthreads();
#pragma unroll
    for (int kk = 0; kk < 2; kk++) {
      int u = kk * 4 + lh;
      short8v af[4], bf[4];
#pragma unroll
      for (int mi = 0; mi < 4; mi++) {
        int r = wid * 64 + mi * 16 + l15;
        af[mi] = *(const short8v*)&As[r * 64 + ((u ^ (r & 7)) << 3)];
      }
#pragma unroll
      for (int ni = 0; ni < 4; ni++) {
        int r = ni * 16 + l15;
        bf[ni] = *(const short8v*)&Bs[r * 64 + ((u ^ (r & 7)) << 3)];
      }
#pragma unroll
      for (int mi = 0; mi < 4; mi++)
#pragma unroll
        for (int ni = 0; ni < 4; ni++)
          acc[mi][ni] = __builtin_amdgcn_mfma_f32_16x16x32_bf16(
              af[mi], bf[ni], acc[mi][ni], 0, 0, 0);
    }
    __syncthreads();
  }

#pragma unroll
  for (int mi = 0; mi < 4; mi++) {
#pragma unroll
    for (int j = 0; j < 4; j++) {
      int gr = rowBase + wid * 64 + mi * 16 + lh * 4 + j;
      if (gr < n) {
        float sc = dinv[gr];
#pragma unroll
        for (int ni = 0; ni < 4; ni++) {
          int gc = ni * 16 + l15;
          if (gc < 40) G2[(size_t)gr * 40 + gc] = acc[mi][ni][j] * sc;
        }
      }
    }
  }
}

// ---------------------------------------------------------------------------
// Aggregate 256-dim from bf16 G, f32 accumulate.
// Col indices loaded once per wave (coalesced) and shfl-broadcast -> gather
// loop has no memory-dependent addressing; 8 gathers in flight.
// ---------------------------------------------------------------------------
template <int RELU, int WF32>
__global__ __launch_bounds__(256) void aggregate_bf16_kernel(
    const short* __restrict__ G, const int* __restrict__ col,
    const int* __restrict__ rs, const int* __restrict__ deg,
    const float* __restrict__ dinv, const float* __restrict__ bias,
    short* __restrict__ Hb, float* __restrict__ Hf, int n) {
  int wid = threadIdx.x >> 6;
  int lane = threadIdx.x & 63;
  int v = blockIdx.x * 4 + wid;
  if (v >= n) return;
  short4v g = *(const short4v*)(G + (size_t)v * 256 + lane * 4);
  float a0 = bf2f(g[0]), a1 = bf2f(g[1]), a2 = bf2f(g[2]), a3 = bf2f(g[3]);
  int base = rs[v], cnt = deg[v];
  for (int i0 = 0; i0 < cnt; i0 += 64) {
    int rem = cnt - i0; if (rem > 64) rem = 64;
    int ci = col[base + i0 + (lane < rem ? lane : 0)];
    int i = 0;
    for (; i + 8 <= rem; i += 8) {
      int u0 = __shfl(ci, i + 0), u1 = __shfl(ci, i + 1);
      int u2 = __shfl(ci, i + 2), u3 = __shfl(ci, i + 3);
      int u4 = __shfl(ci, i + 4), u5 = __shfl(ci, i + 5);
      int u6 = __shfl(ci, i + 6), u7 = __shfl(ci, i + 7);
      short4v m0 = *(const short4v*)(G + (size_t)u0 * 256 + lane * 4);
      short4v m1 = *(const short4v*)(G + (size_t)u1 * 256 + lane * 4);
      short4v m2 = *(const short4v*)(G + (size_t)u2 * 256 + lane * 4);
      short4v m3 = *(const short4v*)(G + (size_t)u3 * 256 + lane * 4);
      short4v m4 = *(const short4v*)(G + (size_t)u4 * 256 + lane * 4);
      short4v m5 = *(const short4v*)(G + (size_t)u5 * 256 + lane * 4);
      short4v m6 = *(const short4v*)(G + (size_t)u6 * 256 + lane * 4);
      short4v m7 = *(const short4v*)(G + (size_t)u7 * 256 + lane * 4);
      a0 += bf2f(m0[0]) + bf2f(m1[0]) + bf2f(m2[0]) + bf2f(m3[0])
          + bf2f(m4[0]) + bf2f(m5[0]) + bf2f(m6[0]) + bf2f(m7[0]);
      a1 += bf2f(m0[1]) + bf2f(m1[1]) + bf2f(m2[1]) + bf2f(m3[1])
          + bf2f(m4[1]) + bf2f(m5[1]) + bf2f(m6[1]) + bf2f(m7[1]);
      a2 += bf2f(m0[2]) + bf2f(m1[2]) + bf2f(m2[2]) + bf2f(m3[2])
          + bf2f(m4[2]) + bf2f(m5[2]) + bf2f(m6[2]) + bf2f(m7[2]);
      a3 += bf2f(m0[3]) + bf2f(m1[3]) + bf2f(m2[3]) + bf2f(m3[3])
          + bf2f(m4[3]) + bf2f(m5[3]) + bf2f(m6[3]) + bf2f(m7[3]);
    }
    for (; i < rem; i++) {
      int u = __shfl(ci, i);
      short4v m = *(const short4v*)(G + (size_t)u * 256 + lane * 4);
      a0 += bf2f(m[0]); a1 += bf2f(m[1]); a2 += bf2f(m[2]); a3 += bf2f(m[3]);
    }
  }
  float s = dinv[v];
  float4 b4 = ((const float4*)bias)[lane];
  float o0 = a0 * s + b4.x, o1 = a1 * s + b4.y, o2 = a2 * s + b4.z, o3 = a3 * s + b4.w;
  if (RELU) {
    o0 = fmaxf(o0, 0.f); o1 = fmaxf(o1, 0.f);
    o2 = fmaxf(o2, 0.f); o3 = fmaxf(o3, 0.f);
  }
  short4v ob; ob[0] = f2bf(o0); ob[1] = f2bf(o1); ob[2] = f2bf(o2); ob[3] = f2bf(o3);
  *(short4v*)(Hb + (size_t)v * 256 + lane * 4) = ob;
  if (WF32) {
    float4 of; of.x = o0; of.y = o1; of.z = o2; of.w = o3;
    *(float4*)(Hf + (size_t)v * 256 + lane * 4) = of;
  }
}

// ---------------------------------------------------------------------------
// Aggregate 40-dim + bias + log_softmax, shfl-broadcast indices.
// ---------------------------------------------------------------------------
__global__ __launch_bounds__(256) void agg40_lsm_kernel(
    const float* __restrict__ G2, const int* __restrict__ col,
    const int* __restrict__ rs, const int* __restrict__ deg,
    const float* __restrict__ dinv, const float* __restrict__ b2,
    float* __restrict__ out, int n) {
  int wid = threadIdx.x >> 6;
  int lane = threadIdx.x & 63;
  int v = blockIdx.x * 4 + wid;
  if (v >= n) return;
  bool act = lane < 40;
  int ln = act ? lane : 0;
  float acc = act ? G2[(size_t)v * 40 + lane] : 0.f;
  int base = rs[v], cnt = deg[v];
  for (int i0 = 0; i0 < cnt; i0 += 64) {
    int rem = cnt - i0; if (rem > 64) rem = 64;
    int ci = col[base + i0 + (lane < rem ? lane : 0)];
    int i = 0;
    for (; i + 4 <= rem; i += 4) {
      int u0 = __shfl(ci, i + 0), u1 = __shfl(ci, i + 1);
      int u2 = __shfl(ci, i + 2), u3 = __shfl(ci, i + 3);
      float x0 = G2[(size_t)u0 * 40 + ln];
      float x1 = G2[(size_t)u1 * 40 + ln];
      float x2 = G2[(size_t)u2 * 40 + ln];
      float x3 = G2[(size_t)u3 * 40 + ln];
      acc += x0 + x1 + x2 + x3;
    }
    for (; i < rem; i++) {
      int u = __shfl(ci, i);
      acc += G2[(size_t)u * 40 + ln];
    }
  }
  float val;
  if (act) val = acc * dinv[v] + b2[lane];
  else val = -INFINITY;
  float m = val;
  for (int off = 32; off; off >>= 1) m = fmaxf(m, __shfl_xor(m, off, 64));
  float e = act ? expf(val - m) : 0.f;
  float ssum = e;
  for (int off = 32; off; off >>= 1) ssum += __shfl_xor(ssum, off, 64);
  if (act) out[(size_t)v * 40 + lane] = val - m - logf(ssum);
}

// ---------------------------------------------------------------------------

static inline size_t alignup(size_t x) { return (x + 255) & ~(size_t)255; }

extern "C" void kernel_launch(void* const* d_in, const int* in_sizes, int n_in,
                              void* d_out, int out_size, void* d_ws, size_t ws_size,
                              hipStream_t stream) {
  const float* x  = (const float*)d_in[0];
  const int*   ei = (const int*)d_in[1];
  const float* W1 = (const float*)d_in[2];
  const float* b1 = (const float*)d_in[3];
  const float* Wi = (const float*)d_in[4];
  const float* bi = (const float*)d_in[5];
  const float* W2 = (const float*)d_in[6];
  const float* b2 = (const float*)d_in[7];

  const int in_d = 512, mid_d = 256, out_d = 40;
  int n = in_sizes[0] / in_d;       // 100000
  int E = in_sizes[1] / 2;          // 1600000
  const int* src = ei;
  const int* dst = ei + E;

  float* out_lsm = (float*)d_out;                        // n*40
  float* emb     = (float*)d_out + (size_t)n * out_d;    // n*256

  char* w = (char*)d_ws;
  float* dinv  = (float*)w;  w += alignup((size_t)n * 4);
  int* deg     = (int*)w;    w += alignup((size_t)n * 4);
  int* rs      = (int*)w;    w += alignup((size_t)n * 4);
  int* cursor  = (int*)w;    w += alignup((size_t)n * 4);
  int* colidx  = (int*)w;    w += alignup((size_t)E * 4);
  int* bsum    = (int*)w;    w += alignup(128 * 4);
  short* W1t   = (short*)w;  w += alignup((size_t)mid_d * in_d * 2);
  short* Wit   = (short*)w;  w += alignup((size_t)mid_d * mid_d * 2);
  short* W2t   = (short*)w;  w += alignup((size_t)64 * mid_d * 2);
  short* Gb    = (short*)w;  w += alignup((size_t)n * mid_d * 2);
  short* Hb    = (short*)w;  w += alignup((size_t)n * mid_d * 2);
  float* G2    = (float*)Gb;   // alias: Gb dead when final gemm runs

  int nb = (n + SCAN_T - 1) / SCAN_T;

  hipMemsetAsync(deg, 0, (size_t)n * 4, stream);
  hipMemsetAsync(cursor, 0, (size_t)n * 4, stream);
  count_deg_kernel<<<2048, 256, 0, stream>>>(dst, deg, E);
  dinv_kernel<<<(n + 255) / 256, 256, 0, stream>>>(deg, dinv, n);
  scan_blocks_kernel<<<nb, SCAN_T, 0, stream>>>(deg, rs, bsum, n);
  scan_bsum_kernel<<<1, 128, 0, stream>>>(bsum, nb);
  add_off_kernel<<<(n + 255) / 256, 256, 0, stream>>>(rs, bsum, n);
  fill_csr_kernel<<<2048, 256, 0, stream>>>(src, dst, rs, cursor, colidx, E);

  convert_wt_kernel<<<(in_d * mid_d + 255) / 256, 256, 0, stream>>>(W1, W1t, in_d, mid_d);
  convert_wt_kernel<<<(mid_d * mid_d + 255) / 256, 256, 0, stream>>>(Wi, Wit, mid_d, mid_d);
  convert_w2t_kernel<<<(64 * mid_d + 255) / 256, 256, 0, stream>>>(W2, W2t);

  int ggrid = (n + 63) / 64;
  int agg_grid = (n + 3) / 4;

  // conv1
  gemm_mfma_kernel<512, true><<<ggrid, 256, 0, stream>>>(x, W1t, dinv, Gb, n);
  aggregate_bf16_kernel<0, 0><<<agg_grid, 256, 0, stream>>>(
      Gb, colidx, rs, deg, dinv, b1, Hb, nullptr, n);
  // conv2..3
  for (int l = 0; l < 2; l++) {
    gemm_mfma_kernel<256, false><<<ggrid, 256, 0, stream>>>(Hb, Wit, dinv, Gb, n);
    aggregate_bf16_kernel<1, 0><<<agg_grid, 256, 0, stream>>>(
        Gb, colidx, rs, deg, dinv, bi, Hb, nullptr, n);
  }
  // conv4 (+ f32 emb)
  gemm_mfma_kernel<256, false><<<ggrid, 256, 0, stream>>>(Hb, Wit, dinv, Gb, n);
  aggregate_bf16_kernel<1, 1><<<agg_grid, 256, 0, stream>>>(
      Gb, colidx, rs, deg, dinv, bi, Hb, emb, n);

  // conv5: MFMA projection + lsm aggregate
  gemm_mfma40_kernel<<<(n + 255) / 256, 256, 0, stream>>>(Hb, W2t, dinv, G2, n);
  agg40_lsm_kernel<<<agg_grid, 256, 0, stream>>>(G2, colidx, rs, deg, dinv, b2, out_lsm, n);
}

// Round 5
// 771.300 us; speedup vs baseline: 3.0875x; 1.1893x over previous
//
#include <hip/hip_runtime.h>
#include <cmath>

typedef __attribute__((ext_vector_type(8))) short short8v;
typedef __attribute__((ext_vector_type(4))) short short4v;
typedef __attribute__((ext_vector_type(4))) float f32x4;

__device__ inline short f2bf(float f) {
  union { float f; unsigned u; } a; a.f = f;
  unsigned r = a.u + 0x7FFF + ((a.u >> 16) & 1);   // RTN-even
  return (short)(r >> 16);
}
__device__ inline float bf2f(short b) {
  union { unsigned u; float f; } a; a.u = ((unsigned)(unsigned short)b) << 16;
  return a.f;
}

// ---------------------------------------------------------------------------
// Graph build
// ---------------------------------------------------------------------------
__global__ void count_deg_kernel(const int* __restrict__ dst, int* __restrict__ deg, int e) {
  int i = blockIdx.x * blockDim.x + threadIdx.x;
  int stride = gridDim.x * blockDim.x;
  for (; i < e; i += stride) atomicAdd(&deg[dst[i]], 1);
}

__global__ void dinv_kernel(const int* __restrict__ deg, float* __restrict__ dinv, int n) {
  int i = blockIdx.x * blockDim.x + threadIdx.x;
  if (i < n) dinv[i] = rsqrtf((float)deg[i] + 1.0f);
}

#define SCAN_T 1024
__global__ void scan_blocks_kernel(const int* __restrict__ deg, int* __restrict__ rs,
                                   int* __restrict__ bsum, int n) {
  __shared__ int s[SCAN_T];
  int t = threadIdx.x;
  int i = blockIdx.x * SCAN_T + t;
  int own = (i < n) ? deg[i] : 0;
  s[t] = own;
  for (int off = 1; off < SCAN_T; off <<= 1) {
    __syncthreads();
    int add = (t >= off) ? s[t - off] : 0;
    __syncthreads();
    s[t] += add;
  }
  if (i < n) rs[i] = s[t] - own;
  if (t == SCAN_T - 1) bsum[blockIdx.x] = s[t];
}

__global__ void scan_bsum_kernel(int* __restrict__ bsum, int nb) {
  __shared__ int s[128];
  int t = threadIdx.x;
  int v = (t < nb) ? bsum[t] : 0;
  s[t] = v;
  for (int off = 1; off < 128; off <<= 1) {
    __syncthreads();
    int add = (t >= off) ? s[t - off] : 0;
    __syncthreads();
    s[t] += add;
  }
  if (t < nb) bsum[t] = s[t] - v;
}

__global__ void add_off_kernel(int* __restrict__ rs, const int* __restrict__ bsum, int n) {
  int i = blockIdx.x * blockDim.x + threadIdx.x;
  if (i < n) rs[i] += bsum[i >> 10];
}

__global__ void fill_csr_kernel(const int* __restrict__ src, const int* __restrict__ dst,
                                const int* __restrict__ rs, int* __restrict__ cursor,
                                int* __restrict__ col, int e) {
  int i = blockIdx.x * blockDim.x + threadIdx.x;
  int stride = gridDim.x * blockDim.x;
  for (; i < e; i += stride) {
    int d = dst[i];
    int p = rs[d] + atomicAdd(&cursor[d], 1);
    col[p] = src[i];
  }
}

// ---------------------------------------------------------------------------
// Weight converts
// ---------------------------------------------------------------------------
__global__ void convert_wt_kernel(const float* __restrict__ W, short* __restrict__ Wt,
                                  int K, int N) {
  int i = blockIdx.x * blockDim.x + threadIdx.x;
  if (i < K * N) {
    int k = i / N, nn = i - k * N;
    Wt[nn * K + k] = f2bf(W[i]);
  }
}

// W2 [256][40] f32 -> W2t [64][256] bf16, zero-padded cols 40..63
__global__ void convert_w2t_kernel(const float* __restrict__ W2, short* __restrict__ W2t) {
  int i = blockIdx.x * blockDim.x + threadIdx.x;
  if (i < 64 * 256) {
    int c = i >> 8, k = i & 255;
    W2t[i] = (c < 40) ? f2bf(W2[k * 40 + c]) : (short)0;
  }
}

// ---------------------------------------------------------------------------
// MFMA GEMM with int8 quantizing epilogue:
//   val[r,c] = (A[r,:K] @ W[:K,c]) ; row absmax -> q = rint(val*127/cmax)
//   G8[r,c] = q (int8);  gscale[r] = dinv[r]*cmax/127
// so dequant q*gscale[r] == val*dinv[r] (the old bf16 G value).
// BM=64 x BN=256 (wave per 64-col slab), BK=64, XOR-swizzled LDS.
// ---------------------------------------------------------------------------
template <int K, bool AF32>
__global__ __launch_bounds__(256, 3) void gemm_mfma_kernel(
    const void* __restrict__ Aptr, const short* __restrict__ Wt,
    const float* __restrict__ dinv, char* __restrict__ G8,
    float* __restrict__ gscale, int n) {
  __shared__ short As[64 * 64];    // 8 KB
  __shared__ short Bs[256 * 64];   // 32 KB
  __shared__ float rmax[4][64];    // 1 KB: per-wave per-row absmax
  int tid = threadIdx.x;
  int lane = tid & 63, wid = tid >> 6;
  int wn = wid;
  int l15 = lane & 15, lh = lane >> 4;
  int rowBase = blockIdx.x * 64;

  f32x4 acc[4][4];
#pragma unroll
  for (int mi = 0; mi < 4; mi++)
#pragma unroll
    for (int ni = 0; ni < 4; ni++) acc[mi][ni] = (f32x4){0.f, 0.f, 0.f, 0.f};

  for (int kt = 0; kt < K; kt += 64) {
#pragma unroll
    for (int i = 0; i < 2; i++) {
      int s = tid + i * 256;
      int r = s >> 3, u = s & 7;
      int gr = rowBase + r; if (gr >= n) gr = n - 1;
      short8v v;
      if constexpr (AF32) {
        const float* ap = (const float*)Aptr + (size_t)gr * K + kt + u * 8;
        float4 f0 = *(const float4*)ap;
        float4 f1 = *(const float4*)(ap + 4);
        v[0] = f2bf(f0.x); v[1] = f2bf(f0.y); v[2] = f2bf(f0.z); v[3] = f2bf(f0.w);
        v[4] = f2bf(f1.x); v[5] = f2bf(f1.y); v[6] = f2bf(f1.z); v[7] = f2bf(f1.w);
      } else {
        v = *(const short8v*)((const short*)Aptr + (size_t)gr * K + kt + u * 8);
      }
      *(short8v*)&As[r * 64 + ((u ^ (r & 7)) << 3)] = v;
    }
#pragma unroll
    for (int i = 0; i < 8; i++) {
      int s = tid + i * 256;
      int r = s >> 3, u = s & 7;
      short8v v = *(const short8v*)(Wt + (size_t)r * K + kt + u * 8);
      *(short8v*)&Bs[r * 64 + ((u ^ (r & 7)) << 3)] = v;
    }
    __syncthreads();
#pragma unroll
    for (int kk = 0; kk < 2; kk++) {
      int u = kk * 4 + lh;
      short8v af[4], bf[4];
#pragma unroll
      for (int mi = 0; mi < 4; mi++) {
        int r = mi * 16 + l15;
        af[mi] = *(const short8v*)&As[r * 64 + ((u ^ (r & 7)) << 3)];
      }
#pragma unroll
      for (int ni = 0; ni < 4; ni++) {
        int r = wn * 64 + ni * 16 + l15;
        bf[ni] = *(const short8v*)&Bs[r * 64 + ((u ^ (r & 7)) << 3)];
      }
#pragma unroll
      for (int mi = 0; mi < 4; mi++)
#pragma unroll
        for (int ni = 0; ni < 4; ni++)
          acc[mi][ni] = __builtin_amdgcn_mfma_f32_16x16x32_bf16(
              af[mi], bf[ni], acc[mi][ni], 0, 0, 0);
    }
    __syncthreads();
  }

  // ---- quantizing epilogue ----
  // per-(mi,j) row: local absmax over this wave's 64-col slab
#pragma unroll
  for (int mi = 0; mi < 4; mi++) {
#pragma unroll
    for (int j = 0; j < 4; j++) {
      float mx = 0.f;
#pragma unroll
      for (int ni = 0; ni < 4; ni++) mx = fmaxf(mx, fabsf(acc[mi][ni][j]));
      // reduce across the 16-lane group (same lh)
      for (int off = 1; off < 16; off <<= 1)
        mx = fmaxf(mx, __shfl_xor(mx, off, 64));
      if (l15 == 0) rmax[wn][mi * 16 + lh * 4 + j] = mx;
    }
  }
  __syncthreads();
#pragma unroll
  for (int mi = 0; mi < 4; mi++) {
#pragma unroll
    for (int j = 0; j < 4; j++) {
      int r = mi * 16 + lh * 4 + j;
      int gr = rowBase + r;
      if (gr < n) {
        float cmax = fmaxf(fmaxf(rmax[0][r], rmax[1][r]),
                           fmaxf(rmax[2][r], rmax[3][r]));
        float inv = (cmax > 0.f) ? 127.f / cmax : 0.f;
        if (wn == 0 && l15 == 0)
          gscale[gr] = dinv[gr] * cmax * (1.f / 127.f);
#pragma unroll
        for (int ni = 0; ni < 4; ni++) {
          int gc = wn * 64 + ni * 16 + l15;
          int q = (int)rintf(acc[mi][ni][j] * inv);
          G8[(size_t)gr * 256 + gc] = (char)q;
        }
      }
    }
  }
}

// ---------------------------------------------------------------------------
// Final MFMA GEMM: G2b[r, 0:40] = bf16( (Hb[r,:256] @ W2[:256,0:40]) * dinv[r] )
// ---------------------------------------------------------------------------
__global__ __launch_bounds__(256, 3) void gemm_mfma40_kernel(
    const short* __restrict__ Hb, const short* __restrict__ W2t,
    const float* __restrict__ dinv, short* __restrict__ G2b, int n) {
  __shared__ short As[256 * 64];   // 32 KB
  __shared__ short Bs[64 * 64];    // 8 KB
  int tid = threadIdx.x;
  int lane = tid & 63, wid = tid >> 6;
  int l15 = lane & 15, lh = lane >> 4;
  int rowBase = blockIdx.x * 256;

  f32x4 acc[4][4];
#pragma unroll
  for (int mi = 0; mi < 4; mi++)
#pragma unroll
    for (int ni = 0; ni < 4; ni++) acc[mi][ni] = (f32x4){0.f, 0.f, 0.f, 0.f};

  for (int kt = 0; kt < 256; kt += 64) {
#pragma unroll
    for (int i = 0; i < 8; i++) {
      int s = tid + i * 256;
      int r = s >> 3, u = s & 7;
      int gr = rowBase + r; if (gr >= n) gr = n - 1;
      short8v v = *(const short8v*)(Hb + (size_t)gr * 256 + kt + u * 8);
      *(short8v*)&As[r * 64 + ((u ^ (r & 7)) << 3)] = v;
    }
#pragma unroll
    for (int i = 0; i < 2; i++) {
      int s = tid + i * 256;
      int r = s >> 3, u = s & 7;
      short8v v = *(const short8v*)(W2t + (size_t)r * 256 + kt + u * 8);
      *(short8v*)&Bs[r * 64 + ((u ^ (r & 7)) << 3)] = v;
    }
    __syncthreads();
#pragma unroll
    for (int kk = 0; kk < 2; kk++) {
      int u = kk * 4 + lh;
      short8v af[4], bf[4];
#pragma unroll
      for (int mi = 0; mi < 4; mi++) {
        int r = wid * 64 + mi * 16 + l15;
        af[mi] = *(const short8v*)&As[r * 64 + ((u ^ (r & 7)) << 3)];
      }
#pragma unroll
      for (int ni = 0; ni < 4; ni++) {
        int r = ni * 16 + l15;
        bf[ni] = *(const short8v*)&Bs[r * 64 + ((u ^ (r & 7)) << 3)];
      }
#pragma unroll
      for (int mi = 0; mi < 4; mi++)
#pragma unroll
        for (int ni = 0; ni < 4; ni++)
          acc[mi][ni] = __builtin_amdgcn_mfma_f32_16x16x32_bf16(
              af[mi], bf[ni], acc[mi][ni], 0, 0, 0);
    }
    __syncthreads();
  }

#pragma unroll
  for (int mi = 0; mi < 4; mi++) {
#pragma unroll
    for (int j = 0; j < 4; j++) {
      int gr = rowBase + wid * 64 + mi * 16 + lh * 4 + j;
      if (gr < n) {
        float sc = dinv[gr];
#pragma unroll
        for (int ni = 0; ni < 4; ni++) {
          int gc = ni * 16 + l15;
          if (gc < 40) G2b[(size_t)gr * 40 + gc] = f2bf(acc[mi][ni][j] * sc);
        }
      }
    }
  }
}

// ---------------------------------------------------------------------------
// Aggregate 256-dim from int8 G + per-row scale, f32 accumulate.
// Row = 256 B; wave reads 4 B/lane. Dequant: a += q * gscale[u].
// ---------------------------------------------------------------------------
__device__ inline void dq_acc(int w, float s, float& a0, float& a1,
                              float& a2, float& a3) {
  a0 += (float)(signed char)(w & 0xff) * s;
  a1 += (float)(signed char)((w >> 8) & 0xff) * s;
  a2 += (float)(signed char)((w >> 16) & 0xff) * s;
  a3 += (float)(signed char)(w >> 24) * s;
}

template <int RELU, int WF32>
__global__ __launch_bounds__(256) void aggregate_i8_kernel(
    const char* __restrict__ G8, const float* __restrict__ gsc,
    const int* __restrict__ col, const int* __restrict__ rs,
    const int* __restrict__ deg, const float* __restrict__ dinv,
    const float* __restrict__ bias, short* __restrict__ Hb,
    float* __restrict__ Hf, int n) {
  int wid = threadIdx.x >> 6;
  int lane = threadIdx.x & 63;
  int v = blockIdx.x * 4 + wid;
  if (v >= n) return;
  float a0 = 0.f, a1 = 0.f, a2 = 0.f, a3 = 0.f;
  {
    int w = *(const int*)(G8 + (size_t)v * 256 + lane * 4);
    dq_acc(w, gsc[v], a0, a1, a2, a3);
  }
  int base = rs[v], cnt = deg[v];
  for (int i0 = 0; i0 < cnt; i0 += 64) {
    int rem = cnt - i0; if (rem > 64) rem = 64;
    int ci = col[base + i0 + (lane < rem ? lane : 0)];
    int i = 0;
    for (; i + 8 <= rem; i += 8) {
      int u0 = __shfl(ci, i + 0), u1 = __shfl(ci, i + 1);
      int u2 = __shfl(ci, i + 2), u3 = __shfl(ci, i + 3);
      int u4 = __shfl(ci, i + 4), u5 = __shfl(ci, i + 5);
      int u6 = __shfl(ci, i + 6), u7 = __shfl(ci, i + 7);
      int w0 = *(const int*)(G8 + (size_t)u0 * 256 + lane * 4);
      int w1 = *(const int*)(G8 + (size_t)u1 * 256 + lane * 4);
      int w2 = *(const int*)(G8 + (size_t)u2 * 256 + lane * 4);
      int w3 = *(const int*)(G8 + (size_t)u3 * 256 + lane * 4);
      int w4 = *(const int*)(G8 + (size_t)u4 * 256 + lane * 4);
      int w5 = *(const int*)(G8 + (size_t)u5 * 256 + lane * 4);
      int w6 = *(const int*)(G8 + (size_t)u6 * 256 + lane * 4);
      int w7 = *(const int*)(G8 + (size_t)u7 * 256 + lane * 4);
      float s0 = gsc[u0], s1 = gsc[u1], s2 = gsc[u2], s3 = gsc[u3];
      float s4 = gsc[u4], s5 = gsc[u5], s6 = gsc[u6], s7 = gsc[u7];
      dq_acc(w0, s0, a0, a1, a2, a3);
      dq_acc(w1, s1, a0, a1, a2, a3);
      dq_acc(w2, s2, a0, a1, a2, a3);
      dq_acc(w3, s3, a0, a1, a2, a3);
      dq_acc(w4, s4, a0, a1, a2, a3);
      dq_acc(w5, s5, a0, a1, a2, a3);
      dq_acc(w6, s6, a0, a1, a2, a3);
      dq_acc(w7, s7, a0, a1, a2, a3);
    }
    for (; i < rem; i++) {
      int u = __shfl(ci, i);
      int w = *(const int*)(G8 + (size_t)u * 256 + lane * 4);
      dq_acc(w, gsc[u], a0, a1, a2, a3);
    }
  }
  float s = dinv[v];
  float4 b4 = ((const float4*)bias)[lane];
  float o0 = a0 * s + b4.x, o1 = a1 * s + b4.y, o2 = a2 * s + b4.z, o3 = a3 * s + b4.w;
  if (RELU) {
    o0 = fmaxf(o0, 0.f); o1 = fmaxf(o1, 0.f);
    o2 = fmaxf(o2, 0.f); o3 = fmaxf(o3, 0.f);
  }
  short4v ob; ob[0] = f2bf(o0); ob[1] = f2bf(o1); ob[2] = f2bf(o2); ob[3] = f2bf(o3);
  *(short4v*)(Hb + (size_t)v * 256 + lane * 4) = ob;
  if (WF32) {
    float4 of; of.x = o0; of.y = o1; of.z = o2; of.w = o3;
    *(float4*)(Hf + (size_t)v * 256 + lane * 4) = of;
  }
}

// ---------------------------------------------------------------------------
// Aggregate 40-dim (bf16 rows) + bias + log_softmax.
// ---------------------------------------------------------------------------
__global__ __launch_bounds__(256) void agg40_lsm_kernel(
    const short* __restrict__ G2b, const int* __restrict__ col,
    const int* __restrict__ rs, const int* __restrict__ deg,
    const float* __restrict__ dinv, const float* __restrict__ b2,
    float* __restrict__ out, int n) {
  int wid = threadIdx.x >> 6;
  int lane = threadIdx.x & 63;
  int v = blockIdx.x * 4 + wid;
  if (v >= n) return;
  bool act = lane < 40;
  int ln = act ? lane : 0;
  float acc = act ? bf2f(G2b[(size_t)v * 40 + lane]) : 0.f;
  int base = rs[v], cnt = deg[v];
  for (int i0 = 0; i0 < cnt; i0 += 64) {
    int rem = cnt - i0; if (rem > 64) rem = 64;
    int ci = col[base + i0 + (lane < rem ? lane : 0)];
    int i = 0;
    for (; i + 4 <= rem; i += 4) {
      int u0 = __shfl(ci, i + 0), u1 = __shfl(ci, i + 1);
      int u2 = __shfl(ci, i + 2), u3 = __shfl(ci, i + 3);
      float x0 = bf2f(G2b[(size_t)u0 * 40 + ln]);
      float x1 = bf2f(G2b[(size_t)u1 * 40 + ln]);
      float x2 = bf2f(G2b[(size_t)u2 * 40 + ln]);
      float x3 = bf2f(G2b[(size_t)u3 * 40 + ln]);
      acc += x0 + x1 + x2 + x3;
    }
    for (; i < rem; i++) {
      int u = __shfl(ci, i);
      acc += bf2f(G2b[(size_t)u * 40 + ln]);
    }
  }
  float val;
  if (act) val = acc * dinv[v] + b2[lane];
  else val = -INFINITY;
  float m = val;
  for (int off = 32; off; off >>= 1) m = fmaxf(m, __shfl_xor(m, off, 64));
  float e = act ? expf(val - m) : 0.f;
  float ssum = e;
  for (int off = 32; off; off >>= 1) ssum += __shfl_xor(ssum, off, 64);
  if (act) out[(size_t)v * 40 + lane] = val - m - logf(ssum);
}

// ---------------------------------------------------------------------------

static inline size_t alignup(size_t x) { return (x + 255) & ~(size_t)255; }

extern "C" void kernel_launch(void* const* d_in, const int* in_sizes, int n_in,
                              void* d_out, int out_size, void* d_ws, size_t ws_size,
                              hipStream_t stream) {
  const float* x  = (const float*)d_in[0];
  const int*   ei = (const int*)d_in[1];
  const float* W1 = (const float*)d_in[2];
  const float* b1 = (const float*)d_in[3];
  const float* Wi = (const float*)d_in[4];
  const float* bi = (const float*)d_in[5];
  const float* W2 = (const float*)d_in[6];
  const float* b2 = (const float*)d_in[7];

  const int in_d = 512, mid_d = 256, out_d = 40;
  int n = in_sizes[0] / in_d;       // 100000
  int E = in_sizes[1] / 2;          // 1600000
  const int* src = ei;
  const int* dst = ei + E;

  float* out_lsm = (float*)d_out;                        // n*40
  float* emb     = (float*)d_out + (size_t)n * out_d;    // n*256

  char* w = (char*)d_ws;
  float* dinv  = (float*)w;  w += alignup((size_t)n * 4);
  int* deg     = (int*)w;    w += alignup((size_t)n * 4);
  int* rs      = (int*)w;    w += alignup((size_t)n * 4);
  int* cursor  = (int*)w;    w += alignup((size_t)n * 4);
  int* colidx  = (int*)w;    w += alignup((size_t)E * 4);
  int* bsum    = (int*)w;    w += alignup(128 * 4);
  short* W1t   = (short*)w;  w += alignup((size_t)mid_d * in_d * 2);
  short* Wit   = (short*)w;  w += alignup((size_t)mid_d * mid_d * 2);
  short* W2t   = (short*)w;  w += alignup((size_t)64 * mid_d * 2);
  char* G8     = (char*)w;   w += alignup((size_t)n * mid_d);       // int8 g
  float* gsc   = (float*)w;  w += alignup((size_t)n * 4);           // row scales
  short* Hb    = (short*)w;  w += alignup((size_t)n * mid_d * 2);   // bf16 h
  short* G2b   = (short*)G8;  // alias: G8 dead when final gemm runs (needs n*40*2 < n*256)

  int nb = (n + SCAN_T - 1) / SCAN_T;

  hipMemsetAsync(deg, 0, (size_t)n * 4, stream);
  hipMemsetAsync(cursor, 0, (size_t)n * 4, stream);
  count_deg_kernel<<<2048, 256, 0, stream>>>(dst, deg, E);
  dinv_kernel<<<(n + 255) / 256, 256, 0, stream>>>(deg, dinv, n);
  scan_blocks_kernel<<<nb, SCAN_T, 0, stream>>>(deg, rs, bsum, n);
  scan_bsum_kernel<<<1, 128, 0, stream>>>(bsum, nb);
  add_off_kernel<<<(n + 255) / 256, 256, 0, stream>>>(rs, bsum, n);
  fill_csr_kernel<<<2048, 256, 0, stream>>>(src, dst, rs, cursor, colidx, E);

  convert_wt_kernel<<<(in_d * mid_d + 255) / 256, 256, 0, stream>>>(W1, W1t, in_d, mid_d);
  convert_wt_kernel<<<(mid_d * mid_d + 255) / 256, 256, 0, stream>>>(Wi, Wit, mid_d, mid_d);
  convert_w2t_kernel<<<(64 * mid_d + 255) / 256, 256, 0, stream>>>(W2, W2t);

  int ggrid = (n + 63) / 64;
  int agg_grid = (n + 3) / 4;

  // conv1
  gemm_mfma_kernel<512, true><<<ggrid, 256, 0, stream>>>(x, W1t, dinv, G8, gsc, n);
  aggregate_i8_kernel<0, 0><<<agg_grid, 256, 0, stream>>>(
      G8, gsc, colidx, rs, deg, dinv, b1, Hb, nullptr, n);
  // conv2..3
  for (int l = 0; l < 2; l++) {
    gemm_mfma_kernel<256, false><<<ggrid, 256, 0, stream>>>(Hb, Wit, dinv, G8, gsc, n);
    aggregate_i8_kernel<1, 0><<<agg_grid, 256, 0, stream>>>(
        G8, gsc, colidx, rs, deg, dinv, bi, Hb, nullptr, n);
  }
  // conv4 (+ f32 emb)
  gemm_mfma_kernel<256, false><<<ggrid, 256, 0, stream>>>(Hb, Wit, dinv, G8, gsc, n);
  aggregate_i8_kernel<1, 1><<<agg_grid, 256, 0, stream>>>(
      G8, gsc, colidx, rs, deg, dinv, bi, Hb, emb, n);

  // conv5: MFMA projection (bf16 out) + lsm aggregate
  gemm_mfma40_kernel<<<(n + 255) / 256, 256, 0, stream>>>(Hb, W2t, dinv, G2b, n);
  agg40_lsm_kernel<<<agg_grid, 256, 0, stream>>>(G2b, colidx, rs, deg, dinv, b2, out_lsm, n);
}